// Round 2
// 341.600 us; speedup vs baseline: 1.0127x; 1.0127x over previous
//
#include <hip/hip_runtime.h>

// Full output LUT in d_ws: for each 12-bit pattern P, the complete 32-float
// output row [s0: pb0..2,v0..4 | s1: ... | s2 | s3].
// Size: 4096 * 32 floats = 524,288 B.

typedef int   vint4   __attribute__((ext_vector_type(4)));
typedef float vfloat4 __attribute__((ext_vector_type(4)));

__global__ __launch_bounds__(256) void build_lut_kernel(
    const float* __restrict__ pat,   // (4,3,4096)
    const float* __restrict__ pos,   // (4,5,4096)
    const int*   __restrict__ conn,  // (4,5,12)
    float* __restrict__ lut)         // (4096,32)
{
    int t = blockIdx.x * 256 + threadIdx.x;   // 0..16383
    if (t >= 4096 * 4) return;
    int P = t >> 2;          // pattern, 12 bits
    int s = t & 3;           // scale
    int n = s + 1;
    int tn = 3 * n;          // ctx bits
    int in_bits = tn + 3;    // ctx + pbits
    int nb = in_bits < 12 ? in_bits : 12;
    unsigned mask = (1u << tn) - 1u;
    unsigned a = (unsigned)P & mask;          // paddr for this scale

    // pos_in bit j (j<tn) is paddr bit (tn-1-j)
    unsigned posmask = 0;
    for (int j = 0; j < tn; ++j)
        posmask |= ((a >> (tn - 1 - j)) & 1u) << j;

    float outv[8];
    for (int j = 0; j < 3; ++j) {
        float v = pat[(s * 3 + j) * 4096 + (int)a];
        unsigned b = (v > 0.5f) ? 1u : 0u;
        outv[j] = (float)b;
        posmask |= b << (tn + j);
    }
    for (int k = 0; k < 5; ++k) {
        unsigned addr = 0;
        for (int j = 0; j < nb; ++j) {
            int c = conn[(s * 5 + k) * 12 + j] % in_bits;
            addr |= ((posmask >> c) & 1u) << j;
        }
        outv[3 + k] = pos[(s * 5 + k) * 4096 + (int)addr];
    }
    // consecutive threads (same P, s=0..3) write consecutive 32B: coalesced
    float4* d4 = (float4*)(lut + (size_t)P * 32 + s * 8);
    d4[0] = make_float4(outv[0], outv[1], outv[2], outv[3]);
    d4[1] = make_float4(outv[4], outv[5], outv[6], outv[7]);
}

__global__ __launch_bounds__(256) void gather_kernel(
    const int* __restrict__ type_bits,     // (B,12) in {0,1}
    const float4* __restrict__ lut4,       // 4096 * 8 float4
    float4* __restrict__ out4,             // nsamp*8 float4
    int nsamp, long long total4)
{
    __shared__ unsigned pshare[256];
    int t = threadIdx.x;
    long long sample = (long long)blockIdx.x * 256 + t;

    // Pack 12 bits: tb[0] -> bit 11 ... tb[11] -> bit 0. Streaming (nt) loads.
    unsigned P = 0;
    if (sample < nsamp) {
        const vint4* tb4 = (const vint4*)type_bits + sample * 3;  // 48B/sample
        vint4 x = __builtin_nontemporal_load(tb4);
        vint4 y = __builtin_nontemporal_load(tb4 + 1);
        vint4 z = __builtin_nontemporal_load(tb4 + 2);
        P = ((unsigned)x.x << 11) | ((unsigned)x.y << 10) | ((unsigned)x.z << 9) | ((unsigned)x.w << 8)
          | ((unsigned)y.x << 7)  | ((unsigned)y.y << 6)  | ((unsigned)y.z << 5) | ((unsigned)y.w << 4)
          | ((unsigned)z.x << 3)  | ((unsigned)z.y << 2)  | ((unsigned)z.z << 1) |  (unsigned)z.w;
    }
    pshare[t] = P;
    __syncthreads();

    // Thread t owns within-sample chunk c = t&7 (one float4 of the 128B row).
    // The 8 lanes sharing a sample read lut4[Ps*8 + 0..7]: 128B contiguous.
    int c    = t & 7;
    int srow = t >> 3;
    long long outBase = (long long)blockIdx.x * 2048 + t;
#pragma unroll
    for (int i = 0; i < 8; ++i) {
        long long g = outBase + (long long)(i * 256);
        if (g < total4) {
            unsigned Ps = pshare[i * 32 + srow];     // LDS broadcast, conflict-free
            float4 v = lut4[(size_t)Ps * 8 + c];     // L2-resident 512KB table
            __builtin_nontemporal_store(*(const vfloat4*)&v, (vfloat4*)&out4[g]);
        }
    }
}

extern "C" void kernel_launch(void* const* d_in, const int* in_sizes, int n_in,
                              void* d_out, int out_size, void* d_ws, size_t ws_size,
                              hipStream_t stream) {
    const int*   type_bits = (const int*)d_in[0];
    const float* pat       = (const float*)d_in[1];
    const float* pos       = (const float*)d_in[2];
    const int*   conn      = (const int*)d_in[3];
    float* lut = (float*)d_ws;   // needs 524,288 B

    int nsamp = in_sizes[0] / 12;                    // 2,000,000
    long long total4 = (long long)nsamp * 8;         // exact float4 count of out

    build_lut_kernel<<<(4096 * 4 + 255) / 256, 256, 0, stream>>>(pat, pos, conn, lut);
    int nblocks = (nsamp + 255) / 256;
    gather_kernel<<<nblocks, 256, 0, stream>>>(type_bits, (const float4*)lut,
                                               (float4*)d_out, nsamp, total4);
}

// Round 3
// 331.305 us; speedup vs baseline: 1.0442x; 1.0311x over previous
//
#include <hip/hip_runtime.h>

// Full output LUT in d_ws: for each 12-bit pattern P, the complete 32-float
// output row [s0: pb0..2,v0..4 | s1 | s2 | s3]. Size: 4096*32 floats = 512 KB.

typedef int   vint4   __attribute__((ext_vector_type(4)));
typedef float vfloat4 __attribute__((ext_vector_type(4)));

__global__ __launch_bounds__(256) void build_lut_kernel(
    const float* __restrict__ pat,   // (4,3,4096)
    const float* __restrict__ pos,   // (4,5,4096)
    const int*   __restrict__ conn,  // (4,5,12)
    float* __restrict__ lut)         // (4096,32)
{
    int t = blockIdx.x * 256 + threadIdx.x;   // 0..16383
    if (t >= 4096 * 4) return;
    int P = t >> 2;          // pattern, 12 bits
    int s = t & 3;           // scale
    int n = s + 1;
    int tn = 3 * n;          // ctx bits
    int in_bits = tn + 3;    // ctx + pbits
    int nb = in_bits < 12 ? in_bits : 12;
    unsigned mask = (1u << tn) - 1u;
    unsigned a = (unsigned)P & mask;          // paddr for this scale

    // pos_in bit j (j<tn) is paddr bit (tn-1-j)
    unsigned posmask = 0;
    for (int j = 0; j < tn; ++j)
        posmask |= ((a >> (tn - 1 - j)) & 1u) << j;

    float outv[8];
    for (int j = 0; j < 3; ++j) {
        float v = pat[(s * 3 + j) * 4096 + (int)a];
        unsigned b = (v > 0.5f) ? 1u : 0u;
        outv[j] = (float)b;
        posmask |= b << (tn + j);
    }
    for (int k = 0; k < 5; ++k) {
        unsigned addr = 0;
        for (int j = 0; j < nb; ++j) {
            int c = conn[(s * 5 + k) * 12 + j] % in_bits;
            addr |= ((posmask >> c) & 1u) << j;
        }
        outv[3 + k] = pos[(s * 5 + k) * 4096 + (int)addr];
    }
    float4* d4 = (float4*)(lut + (size_t)P * 32 + s * 8);
    d4[0] = make_float4(outv[0], outv[1], outv[2], outv[3]);
    d4[1] = make_float4(outv[4], outv[5], outv[6], outv[7]);
}

__global__ __launch_bounds__(256) void gather_kernel(
    const vint4* __restrict__ tb4,       // type_bits as int4: 3 per sample
    const float4* __restrict__ lut4,     // 4096 * 8 float4 (L2-resident)
    float4* __restrict__ out4,           // nsamp*8 float4
    int nsamp, long long total4)
{
    __shared__ vint4    stage[768];      // 12 KB: this block's 256 samples
    __shared__ unsigned pshare[256];
    int t = threadIdx.x;

    // --- Stage 12 KB of type_bits with exactly-once, fully-sequential nt loads.
    // Lane i of each instruction reads byte 16*i from a contiguous 4 KB span:
    // every 128B line touched by exactly one instruction -> no nt over-fetch.
    long long base  = (long long)blockIdx.x * 768;   // int4 index
    long long limit = (long long)nsamp * 3;
#pragma unroll
    for (int r = 0; r < 3; ++r) {
        long long idx = base + r * 256 + t;
        vint4 v = {0, 0, 0, 0};
        if (idx < limit) v = __builtin_nontemporal_load(tb4 + idx);
        stage[r * 256 + t] = v;
    }
    __syncthreads();

    // --- Pack sample t's 12 bits: tb[0]->bit11 ... tb[11]->bit0.
    vint4 x = stage[t * 3 + 0];
    vint4 y = stage[t * 3 + 1];
    vint4 z = stage[t * 3 + 2];
    unsigned P =
          ((unsigned)x.x << 11) | ((unsigned)x.y << 10) | ((unsigned)x.z << 9) | ((unsigned)x.w << 8)
        | ((unsigned)y.x << 7)  | ((unsigned)y.y << 6)  | ((unsigned)y.z << 5) | ((unsigned)y.w << 4)
        | ((unsigned)z.x << 3)  | ((unsigned)z.y << 2)  | ((unsigned)z.z << 1) |  (unsigned)z.w;
    pshare[t] = P;
    __syncthreads();

    // --- Thread t owns within-sample chunk c = t&7 (one float4 of the 128B row).
    // The 8 lanes sharing a sample read lut4[Ps*8 + 0..7]: 128B contiguous L2 hit.
    int c    = t & 7;
    int srow = t >> 3;
    long long outBase = (long long)blockIdx.x * 2048 + t;
#pragma unroll
    for (int i = 0; i < 8; ++i) {
        long long g = outBase + (long long)(i * 256);
        if (g < total4) {
            unsigned Ps = pshare[i * 32 + srow];       // LDS broadcast, conflict-free
            float4 v = lut4[(size_t)Ps * 8 + c];
            __builtin_nontemporal_store(*(const vfloat4*)&v, (vfloat4*)&out4[g]);
        }
    }
}

extern "C" void kernel_launch(void* const* d_in, const int* in_sizes, int n_in,
                              void* d_out, int out_size, void* d_ws, size_t ws_size,
                              hipStream_t stream) {
    const int*   type_bits = (const int*)d_in[0];
    const float* pat       = (const float*)d_in[1];
    const float* pos       = (const float*)d_in[2];
    const int*   conn      = (const int*)d_in[3];
    float* lut = (float*)d_ws;   // needs 524,288 B

    int nsamp = in_sizes[0] / 12;                    // 2,000,000
    long long total4 = (long long)nsamp * 8;         // exact float4 count of out

    build_lut_kernel<<<(4096 * 4 + 255) / 256, 256, 0, stream>>>(pat, pos, conn, lut);
    int nblocks = (nsamp + 255) / 256;
    gather_kernel<<<nblocks, 256, 0, stream>>>((const vint4*)type_bits,
                                               (const float4*)lut,
                                               (float4*)d_out, nsamp, total4);
}

// Round 4
// 329.568 us; speedup vs baseline: 1.0497x; 1.0053x over previous
//
#include <hip/hip_runtime.h>

// Full output LUT in d_ws: for each 12-bit pattern P, the complete 32-float
// output row [s0: pb0..2,v0..4 | s1 | s2 | s3]. Size: 4096*32 floats = 512 KB.

typedef int   vint4   __attribute__((ext_vector_type(4)));
typedef float vfloat4 __attribute__((ext_vector_type(4)));

__global__ __launch_bounds__(256) void build_lut_kernel(
    const float* __restrict__ pat,   // (4,3,4096)
    const float* __restrict__ pos,   // (4,5,4096)
    const int*   __restrict__ conn,  // (4,5,12)
    float* __restrict__ lut)         // (4096,32)
{
    int t = blockIdx.x * 256 + threadIdx.x;   // 0..16383
    if (t >= 4096 * 4) return;
    int P = t >> 2;          // pattern, 12 bits
    int s = t & 3;           // scale
    int n = s + 1;
    int tn = 3 * n;          // ctx bits
    int in_bits = tn + 3;    // ctx + pbits
    int nb = in_bits < 12 ? in_bits : 12;
    unsigned mask = (1u << tn) - 1u;
    unsigned a = (unsigned)P & mask;          // paddr for this scale

    // pos_in bit j (j<tn) is paddr bit (tn-1-j)
    unsigned posmask = 0;
    for (int j = 0; j < tn; ++j)
        posmask |= ((a >> (tn - 1 - j)) & 1u) << j;

    float outv[8];
    for (int j = 0; j < 3; ++j) {
        float v = pat[(s * 3 + j) * 4096 + (int)a];
        unsigned b = (v > 0.5f) ? 1u : 0u;
        outv[j] = (float)b;
        posmask |= b << (tn + j);
    }
    for (int k = 0; k < 5; ++k) {
        unsigned addr = 0;
        for (int j = 0; j < nb; ++j) {
            int c = conn[(s * 5 + k) * 12 + j] % in_bits;
            addr |= ((posmask >> c) & 1u) << j;
        }
        outv[3 + k] = pos[(s * 5 + k) * 4096 + (int)addr];
    }
    float4* d4 = (float4*)(lut + (size_t)P * 32 + s * 8);
    d4[0] = make_float4(outv[0], outv[1], outv[2], outv[3]);
    d4[1] = make_float4(outv[4], outv[5], outv[6], outv[7]);
}

__global__ __launch_bounds__(256) void gather_kernel(
    const vint4* __restrict__ tb4,       // type_bits as int4: 3 per sample
    const float4* __restrict__ lut4,     // 4096 * 8 float4 (L2-resident)
    float4* __restrict__ out4,           // nsamp*8 float4
    int nsamp)
{
    // pnib[part*256 + sampleLocal] holds the pre-shifted 4-bit nibble of P:
    // part 0 -> bits 11..8, part 1 -> bits 7..4, part 2 -> bits 3..0.
    __shared__ unsigned pnib[768];       // 3 KB
    int t = threadIdx.x;
    bool full = ((long long)(blockIdx.x + 1) * 256) <= (long long)nsamp;

    // --- Stage + pack: exactly-once fully-sequential nt loads (lane i reads
    // byte 16*i of a contiguous 4 KB span), nibble written pre-shifted.
    long long base  = (long long)blockIdx.x * 768;   // int4 index
    long long limit = (long long)nsamp * 3;
#pragma unroll
    for (int r = 0; r < 3; ++r) {
        int l = r * 256 + t;                         // 0..767
        vint4 v = {0, 0, 0, 0};
        if (full || base + l < limit) v = __builtin_nontemporal_load(tb4 + base + l);
        int sl = l / 3, part = l - sl * 3;
        unsigned nib = ((unsigned)v.x << 3) | ((unsigned)v.y << 2)
                     | ((unsigned)v.z << 1) |  (unsigned)v.w;
        pnib[part * 256 + sl] = nib << (8 - 4 * part);
    }
    __syncthreads();

    // --- Thread t owns within-sample chunk c = t&7 (one float4 of the 128B row).
    // The 8 lanes sharing a sample read lut4[Ps*8 + 0..7]: 128B contiguous L2 hit.
    int c    = t & 7;
    int srow = t >> 3;
    const float4* lutc = lut4 + c;
    long long outBase = (long long)blockIdx.x * 2048 + t;

    unsigned Ps[8];
#pragma unroll
    for (int i = 0; i < 8; ++i) {
        int sl = i * 32 + srow;
        // 3 stride-4B LDS reads, broadcast within each 8-lane group: conflict-free
        Ps[i] = pnib[sl] | pnib[256 + sl] | pnib[512 + sl];
    }
    float4 vbuf[8];
#pragma unroll
    for (int i = 0; i < 8; ++i)
        vbuf[i] = lutc[(size_t)Ps[i] * 8];           // all 8 loads in flight

    if (full) {
#pragma unroll
        for (int i = 0; i < 8; ++i)
            __builtin_nontemporal_store(*(const vfloat4*)&vbuf[i],
                                        (vfloat4*)&out4[outBase + (long long)(i * 256)]);
    } else {
        long long total4 = (long long)nsamp * 8;
#pragma unroll
        for (int i = 0; i < 8; ++i) {
            long long g = outBase + (long long)(i * 256);
            if (g < total4)
                __builtin_nontemporal_store(*(const vfloat4*)&vbuf[i],
                                            (vfloat4*)&out4[g]);
        }
    }
}

extern "C" void kernel_launch(void* const* d_in, const int* in_sizes, int n_in,
                              void* d_out, int out_size, void* d_ws, size_t ws_size,
                              hipStream_t stream) {
    const int*   type_bits = (const int*)d_in[0];
    const float* pat       = (const float*)d_in[1];
    const float* pos       = (const float*)d_in[2];
    const int*   conn      = (const int*)d_in[3];
    float* lut = (float*)d_ws;   // needs 524,288 B

    int nsamp = in_sizes[0] / 12;                    // 2,000,000

    build_lut_kernel<<<(4096 * 4 + 255) / 256, 256, 0, stream>>>(pat, pos, conn, lut);
    int nblocks = (nsamp + 255) / 256;
    gather_kernel<<<nblocks, 256, 0, stream>>>((const vint4*)type_bits,
                                               (const float4*)lut,
                                               (float4*)d_out, nsamp);
}